// Round 11
// baseline (518.653 us; speedup 1.0000x reference)
//
#include <hip/hip_runtime.h>
#include <hip/hip_bf16.h>
#include <hip/hip_fp16.h>

// H2GCN inference:
//   r0 = relu(x @ w_embed)                       [N,64]
//   r1 = relu([spmm(a1,r0) | spmm(a2,r0)])       [N,128]
//   r2 = relu([spmm(a1,r1) | spmm(a2,r1)])       [N,256]
//   out = softmax([r0|r1|r2] @ w_classify)       [N,16]
//
// Round-11: histo_rank2 (103us, VALUBusy 0.4%/HBM 0.6% = cross-XCD atomic
// line migration on cnt[]) is ELIMINATED:
//  - per-row counters sharded by XCD: cnt8[s][row], s = blk&7 (same
//    XCD-locality mechanism that fixed bucketize in r10) -> atomic lines
//    stay in one XCD's L2.
//  - the histogram+rank runs INSIDE bucketize (which already streams all
//    edges); rank = shard-local atomic return, payload carries lr|s<<13.
//  - scan_blocks2 merges the 8 shards per row (u16x8 shard-offset table);
//    build_epack: p = rs[row] + so[row*8+s] + lr. Ranks need not preserve
//    edge order (sum is commutative).

#define F_IN 256
#define H_DIM 64
#define CPAD 16  // ints per cursor (64B line)

__device__ __forceinline__ unsigned short f2h(float x) {
  return __half_as_ushort(__float2half(x));
}
__device__ __forceinline__ float h2f(unsigned short u) {
  return __half2float(__ushort_as_half(u));
}
__device__ __forceinline__ int2 nt_ld2(const int2* p) {
  unsigned long long u =
      __builtin_nontemporal_load((const unsigned long long*)p);
  int2 r;
  r.x = (int)(u & 0xFFFFFFFFull);
  r.y = (int)(u >> 32);
  return r;
}

// ---------------- embed GEMM: r0 = relu(x @ w), + f16 mirror ----------
__global__ __launch_bounds__(256) void embed_gemm_relu(
    const float* __restrict__ x, const float* __restrict__ w,
    float* __restrict__ r0, unsigned short* __restrict__ r0h, int n_tiles) {
  __shared__ float ws[F_IN * H_DIM];  // 64 KB
  for (int i = threadIdx.x; i < F_IN * H_DIM / 4; i += 256)
    ((float4*)ws)[i] = ((const float4*)w)[i];
  __syncthreads();
  int lane = threadIdx.x & 63;
  int tile = blockIdx.x * 4 + (threadIdx.x >> 6);
  if (tile >= n_tiles) return;
  int row = tile * 4;
  float xv[4][4];
#pragma unroll
  for (int j = 0; j < 4; ++j)
#pragma unroll
    for (int q = 0; q < 4; ++q)
      xv[j][q] = x[(size_t)(row + j) * F_IN + q * 64 + lane];
  float acc[4] = {0.f, 0.f, 0.f, 0.f};
#pragma unroll
  for (int k = 0; k < 256; ++k) {
    float wk = ws[k * 64 + lane];
#pragma unroll
    for (int j = 0; j < 4; ++j) {
      float xb = __uint_as_float(
          __builtin_amdgcn_readlane(__float_as_uint(xv[j][k >> 6]), k & 63));
      acc[j] = fmaf(xb, wk, acc[j]);
    }
  }
#pragma unroll
  for (int j = 0; j < 4; ++j) {
    float v = fmaxf(acc[j], 0.f);
    r0[(size_t)(row + j) * H_DIM + lane] = v;
    r0h[(size_t)(row + j) * H_DIM + lane] = f2h(v);
  }
}

// ---------------- bucketize + sharded histogram/rank -------------------
// One pass over all edges: rank from XCD-sharded counter (cnt8[s][row],
// s = blk&7 -> counter lines stay in one XCD's L2), wave-ballot append
// into 8 row-range buckets x 8 stripes (cursors 64B-padded).
// Payload: (row | col<<16,  lr|s<<13 | f16val<<16).
__global__ __launch_bounds__(256) void bucketize2(
    const int* __restrict__ i1, const float* __restrict__ v1, int E1,
    int* __restrict__ cnt81, int* __restrict__ scur1, int2* __restrict__ bkt1,
    int sub1, const int* __restrict__ i2, const float* __restrict__ v2,
    int E2, int* __restrict__ cnt82, int* __restrict__ scur2,
    int2* __restrict__ bkt2, int sub2, int PA1, int PAtot, float invchunk,
    int n) {
  int blk = blockIdx.x;
  const int* I;
  const float* V;
  int E, nb, sub;
  int* cnt8;
  int* scur;
  int2* bkt;
  if (blk < PA1) {
    I = i1; V = v1; E = E1; cnt8 = cnt81; scur = scur1; bkt = bkt1;
    sub = sub1; nb = PA1;
  } else {
    I = i2; V = v2; E = E2; cnt8 = cnt82; scur = scur2; bkt = bkt2;
    sub = sub2; nb = PAtot - PA1; blk -= PA1;
  }
  int lane = threadIdx.x & 63;
  int s = blk & 7;  // stripe ~ XCD (round-robin dispatch heuristic)
  int* mycnt = cnt8 + s * n;
  for (int base_i = blk * 256; base_i < E; base_i += nb * 256) {
    int i = base_i + threadIdx.x;
    bool valid = i < E;
    int row = 0, col = 0;
    float v = 0.f;
    int lr = 0;
    if (valid) {
      row = I[i];
      col = I[E + i];
      v = V[i];
      lr = atomicAdd(&mycnt[row], 1);  // XCD-local line -> fast
    }
    int mb = valid ? (int)((float)row * invchunk) : -1;
    int2 pk;
    pk.x = row | (col << 16);
    pk.y = lr | (s << 13) | ((int)f2h(v) << 16);
#pragma unroll
    for (int b = 0; b < 8; ++b) {
      unsigned long long m = __ballot(mb == b);
      if (m) {
        int cnt = __popcll(m);
        int leader = __ffsll((long long)m) - 1;
        int base = 0;
        if (lane == leader) base = atomicAdd(&scur[(b * 8 + s) * CPAD], cnt);
        base = __shfl(base, leader, 64);
        if (mb == b) {
          int rank = __popcll(m & ((1ull << lane) - 1));
          bkt[(size_t)(b * 8 + s) * sub + base + rank] = pk;
        }
      }
    }
  }
}

// ---------------- scan: merge 8 shards/row + exclusive scan ------------
__global__ __launch_bounds__(512) void scan_blocks2(
    const int* __restrict__ c81, int* __restrict__ e1, int* __restrict__ a1,
    unsigned short* __restrict__ so1, const int* __restrict__ c82,
    int* __restrict__ e2, int* __restrict__ a2,
    unsigned short* __restrict__ so2, int n, int NB) {
  const int* c8;
  int* exc;
  int* aux;
  unsigned short* so;
  int blk = blockIdx.x;
  if (blk < NB) {
    c8 = c81; exc = e1; aux = a1; so = so1;
  } else {
    c8 = c82; exc = e2; aux = a2; so = so2; blk -= NB;
  }
  __shared__ int tmp[512];
  int i = blk * 512 + threadIdx.x;
  int v = 0;
  if (i < n) {
    int acc = 0;
    unsigned off[8];
#pragma unroll
    for (int sh = 0; sh < 8; ++sh) {
      off[sh] = (unsigned)acc;
      acc += c8[sh * n + i];
    }
    v = acc;
    uint4 st;
    st.x = off[0] | (off[1] << 16);
    st.y = off[2] | (off[3] << 16);
    st.z = off[4] | (off[5] << 16);
    st.w = off[6] | (off[7] << 16);
    *(uint4*)&so[(size_t)i * 8] = st;
  }
  tmp[threadIdx.x] = v;
  __syncthreads();
#pragma unroll
  for (int d = 1; d < 512; d <<= 1) {
    int t = (threadIdx.x >= d) ? tmp[threadIdx.x - d] : 0;
    __syncthreads();
    tmp[threadIdx.x] += t;
    __syncthreads();
  }
  if (i < n) exc[i] = tmp[threadIdx.x] - v;
  if (threadIdx.x == 511) aux[blk] = tmp[511];
}

__global__ __launch_bounds__(512) void scan_aux2(int* __restrict__ a1,
                                                 int* __restrict__ a2,
                                                 int nblk) {
  int* aux = (blockIdx.x == 0) ? a1 : a2;
  __shared__ int tmp[512];
  int v = (threadIdx.x < nblk) ? aux[threadIdx.x] : 0;
  tmp[threadIdx.x] = v;
  __syncthreads();
#pragma unroll
  for (int d = 1; d < 512; d <<= 1) {
    int t = (threadIdx.x >= d) ? tmp[threadIdx.x - d] : 0;
    __syncthreads();
    tmp[threadIdx.x] += t;
    __syncthreads();
  }
  if (threadIdx.x < nblk) aux[threadIdx.x] = tmp[threadIdx.x] - v;
}

__global__ __launch_bounds__(512) void add_offsets2(
    int* __restrict__ rs1, const int* __restrict__ a1, int E1,
    int* __restrict__ rs2, const int* __restrict__ a2, int E2, int n, int NB) {
  int blk = blockIdx.x;
  int* rs;
  const int* aux;
  int E;
  if (blk < NB) {
    rs = rs1; aux = a1; E = E1;
  } else {
    rs = rs2; aux = a2; E = E2; blk -= NB;
  }
  int i = blk * 512 + threadIdx.x;
  if (i < n) rs[i] += aux[blk];
  if (blk == 0 && threadIdx.x == 0) rs[n] = E;
}

// ---------------- build_epack: per-XCD, rank-based, no atomics ----------
__global__ __launch_bounds__(256) void build_epack2(
    const int* __restrict__ scur1, const int2* __restrict__ bkt1, int sub1,
    const int* __restrict__ rs1, const unsigned short* __restrict__ so1,
    unsigned* __restrict__ ep1, const int* __restrict__ scur2,
    const int2* __restrict__ bkt2, int sub2, const int* __restrict__ rs2,
    const unsigned short* __restrict__ so2, unsigned* __restrict__ ep2,
    int PB1, int PBtot) {
  int blk = blockIdx.x;
  const int* scur;
  const int2* bkt;
  const int* rs;
  const unsigned short* so;
  unsigned* ep;
  int sub, nb;
  if (blk < PB1) {
    scur = scur1; bkt = bkt1; sub = sub1; rs = rs1; so = so1; ep = ep1;
    nb = PB1;
  } else {
    scur = scur2; bkt = bkt2; sub = sub2; rs = rs2; so = so2; ep = ep2;
    nb = PBtot - PB1; blk -= PB1;
  }
  int g = blk & 7;  // bucket == XCD-local row range
  int bg = blk >> 3;
  int gstride = (nb >> 3) * 256;
#pragma unroll 1
  for (int s = 0; s < 8; ++s) {
    int len = scur[(g * 8 + s) * CPAD];
    const int2* bp = bkt + (size_t)(g * 8 + s) * sub;
    for (int i = bg * 256 + threadIdx.x; i < len; i += gstride) {
      int2 be = nt_ld2(&bp[i]);
      int row = be.x & 0xFFFF;
      unsigned col = (unsigned)be.x >> 16;
      int rkbits = be.y & 0xFFFF;
      int sh = (rkbits >> 13) & 7;
      int lr = rkbits & 0x1FFF;
      int p = rs[row] + (int)so[(size_t)row * 8 + sh] + lr;
      ep[p] = ((unsigned)be.y & 0xFFFF0000u) | col;
    }
  }
}

// ---------------- hop1: r0h (f16,[n,64]) -> r1 f32 + r1h f16 ----------
__global__ __launch_bounds__(256) void spmm_h1(
    const int* __restrict__ rs1, const unsigned* __restrict__ ep1,
    const int* __restrict__ rs2, const unsigned* __restrict__ ep2,
    const unsigned short* __restrict__ r0h, float* __restrict__ r1,
    unsigned short* __restrict__ r1h, int n, int SB) {
  const int* rs;
  const unsigned* epack;
  int coff;
  int blk = blockIdx.x;
  if (blk < SB) {
    rs = rs1; epack = ep1; coff = 0;
  } else {
    rs = rs2; epack = ep2; coff = 64; blk -= SB;
  }
  int lane = threadIdx.x & 63;
  int row = blk * 4 + (threadIdx.x >> 6);
  if (row >= n) return;
  int s = rs[row], e = rs[row + 1];
  float acc = 0.f;
  int j = s;
  for (; j + 8 <= e; j += 8) {
    unsigned pk[8];
#pragma unroll
    for (int u = 0; u < 8; ++u) pk[u] = epack[j + u];
    float xg[8];
#pragma unroll
    for (int u = 0; u < 8; ++u)
      xg[u] = h2f(r0h[(size_t)(pk[u] & 0xFFFF) * 64 + lane]);
#pragma unroll
    for (int u = 0; u < 8; ++u)
      acc = fmaf(h2f((unsigned short)(pk[u] >> 16)), xg[u], acc);
  }
  for (; j < e; ++j) {
    unsigned pk = epack[j];
    acc = fmaf(h2f((unsigned short)(pk >> 16)),
               h2f(r0h[(size_t)(pk & 0xFFFF) * 64 + lane]), acc);
  }
  float v = fmaxf(acc, 0.f);
  r1[(size_t)row * 128 + coff + lane] = v;
  r1h[(size_t)row * 128 + coff + lane] = f2h(v);
}

// ---------------- hop2: r1h (f16,[n,128]) -> r2 f32 -------------------
__global__ __launch_bounds__(256) void spmm_h2(
    const int* __restrict__ rs1, const unsigned* __restrict__ ep1,
    const int* __restrict__ rs2, const unsigned* __restrict__ ep2,
    const unsigned short* __restrict__ r1h, float* __restrict__ r2, int n,
    int SB) {
  const int* rs;
  const unsigned* epack;
  int coff;
  int blk = blockIdx.x;
  if (blk < SB) {
    rs = rs1; epack = ep1; coff = 0;
  } else {
    rs = rs2; epack = ep2; coff = 128; blk -= SB;
  }
  int lane = threadIdx.x & 63;
  int row = blk * 4 + (threadIdx.x >> 6);
  if (row >= n) return;
  int s = rs[row], e = rs[row + 1];
  float acc0 = 0.f, acc1 = 0.f;
  int j = s;
  for (; j + 8 <= e; j += 8) {
    unsigned pk[8];
#pragma unroll
    for (int u = 0; u < 8; ++u) pk[u] = epack[j + u];
    unsigned g[8];
#pragma unroll
    for (int u = 0; u < 8; ++u)
      g[u] = *(const unsigned*)&r1h[(size_t)(pk[u] & 0xFFFF) * 128 + lane * 2];
#pragma unroll
    for (int u = 0; u < 8; ++u) {
      float v = h2f((unsigned short)(pk[u] >> 16));
      acc0 = fmaf(v, h2f((unsigned short)(g[u] & 0xFFFF)), acc0);
      acc1 = fmaf(v, h2f((unsigned short)(g[u] >> 16)), acc1);
    }
  }
  for (; j < e; ++j) {
    unsigned pk = epack[j];
    unsigned g = *(const unsigned*)&r1h[(size_t)(pk & 0xFFFF) * 128 + lane * 2];
    float v = h2f((unsigned short)(pk >> 16));
    acc0 = fmaf(v, h2f((unsigned short)(g & 0xFFFF)), acc0);
    acc1 = fmaf(v, h2f((unsigned short)(g >> 16)), acc1);
  }
  float2 st;
  st.x = fmaxf(acc0, 0.f);
  st.y = fmaxf(acc1, 0.f);
  *(float2*)&r2[(size_t)row * 256 + coff + lane * 2] = st;
}

// ---------------- classifier + softmax --------------------------------
__global__ __launch_bounds__(256) void classify_softmax(
    const float* __restrict__ r0, const float* __restrict__ r1,
    const float* __restrict__ r2, const float* __restrict__ wc,
    float* __restrict__ out, int n) {
  __shared__ float wls[448 * 17];  // stride 17: no bank conflict
  for (int i = threadIdx.x; i < 448 * 16; i += 256)
    wls[(i >> 4) * 17 + (i & 15)] = wc[i];
  __syncthreads();
  int lane = threadIdx.x & 63;
  int c = lane & 15;
  int part = lane >> 4;
  int node = blockIdx.x * 4 + (threadIdx.x >> 6);
  if (node >= n) return;

  float acc = 0.f;
  {
    const float* p = r0 + (size_t)node * 64 + part * 16;
#pragma unroll
    for (int j = 0; j < 4; ++j) {
      float4 rv = *(const float4*)(p + 4 * j);
      int fb = part * 16 + 4 * j;
      acc = fmaf(rv.x, wls[(fb + 0) * 17 + c], acc);
      acc = fmaf(rv.y, wls[(fb + 1) * 17 + c], acc);
      acc = fmaf(rv.z, wls[(fb + 2) * 17 + c], acc);
      acc = fmaf(rv.w, wls[(fb + 3) * 17 + c], acc);
    }
  }
  {
    const float* p = r1 + (size_t)node * 128 + part * 32;
#pragma unroll
    for (int j = 0; j < 8; ++j) {
      float4 rv = *(const float4*)(p + 4 * j);
      int fb = 64 + part * 32 + 4 * j;
      acc = fmaf(rv.x, wls[(fb + 0) * 17 + c], acc);
      acc = fmaf(rv.y, wls[(fb + 1) * 17 + c], acc);
      acc = fmaf(rv.z, wls[(fb + 2) * 17 + c], acc);
      acc = fmaf(rv.w, wls[(fb + 3) * 17 + c], acc);
    }
  }
  {
    const float* p = r2 + (size_t)node * 256 + part * 64;
#pragma unroll
    for (int j = 0; j < 16; ++j) {
      float4 rv = *(const float4*)(p + 4 * j);
      int fb = 192 + part * 64 + 4 * j;
      acc = fmaf(rv.x, wls[(fb + 0) * 17 + c], acc);
      acc = fmaf(rv.y, wls[(fb + 1) * 17 + c], acc);
      acc = fmaf(rv.z, wls[(fb + 2) * 17 + c], acc);
      acc = fmaf(rv.w, wls[(fb + 3) * 17 + c], acc);
    }
  }
  acc += __shfl_xor(acc, 16, 64);
  acc += __shfl_xor(acc, 32, 64);
  float m = acc;
#pragma unroll
  for (int d = 1; d < 16; d <<= 1) m = fmaxf(m, __shfl_xor(m, d, 64));
  float ex = __expf(acc - m);
  float s = ex;
#pragma unroll
  for (int d = 1; d < 16; d <<= 1) s += __shfl_xor(s, d, 64);
  if (lane < 16) out[(size_t)node * 16 + c] = ex / s;
}

extern "C" void kernel_launch(void* const* d_in, const int* in_sizes, int n_in,
                              void* d_out, int out_size, void* d_ws, size_t ws_size,
                              hipStream_t stream) {
  const float* x = (const float*)d_in[0];
  const int* a1_idx = (const int*)d_in[1];
  const float* a1_val = (const float*)d_in[2];
  const int* a2_idx = (const int*)d_in[3];
  const float* a2_val = (const float*)d_in[4];
  const float* w_embed = (const float*)d_in[5];
  const float* w_classify = (const float*)d_in[6];
  float* out = (float*)d_out;

  const int n = in_sizes[0] / F_IN;  // 50000 (< 65536: u16 row/col packing)
  const int E1 = in_sizes[2];        // 800000
  const int E2 = in_sizes[4];        // 1600000
  const int chunk = (n + 7) / 8;     // 6250 rows per XCD bucket
  const float invchunk = 1.0f / (float)chunk;
  const int sub1 = E1 / 64 + 4096;   // sub-bucket capacity (8 stripes x 8)
  const int sub2 = E2 / 64 + 4096;

  // workspace layout
  float* r0 = (float*)d_ws;                        // n*64 f32
  float* r1 = r0 + (size_t)n * 64;                 // n*128 f32
  float* r2 = r1 + (size_t)n * 128;                // n*256 f32
  unsigned short* r0h = (unsigned short*)(r2 + (size_t)n * 256);  // n*64
  unsigned short* r1h = r0h + (size_t)n * 64;      // n*128
  int* cnt81 = (int*)(r1h + (size_t)n * 128);      // 8n (XCD-sharded)
  int* cnt82 = cnt81 + (size_t)8 * n;              // 8n
  int* scur = cnt82 + (size_t)8 * n;               // 128 cursors x CPAD
  int* rs1 = scur + 128 * CPAD;                    // n+1
  int* rs2 = rs1 + (n + 1);                        // n+1
  int* aux1 = rs2 + (n + 1);                       // 512
  int* aux2 = aux1 + 512;                          // 512
  unsigned short* so1 = (unsigned short*)(aux2 + 512);  // 8n u16 (16B align)
  unsigned short* so2 = so1 + (size_t)8 * n;       // 8n u16
  unsigned* ep1 = (unsigned*)(so2 + (size_t)8 * n);  // E1 (4B/edge)
  unsigned* ep2 = ep1 + E1;                        // E2
  // buckets ALIAS r2 (dead before spmm_h2 writes r2): 23.4MB <= 51.2MB
  int2* bkt1 = (int2*)r2;                          // 64*sub1 entries
  int2* bkt2 = bkt1 + (size_t)64 * sub1;           // 64*sub2 entries

  auto blocks = [](long long t, int bs) { return (int)((t + bs - 1) / bs); };
  const int NB = blocks(n, 512);     // 98
  const int PA1 = 1024, PA2 = 2048;  // bucketize blocks (mult of 8)
  const int PB1 = 512, PB2 = 1024;   // build_epack blocks (mult of 8)
  const int SB = blocks(n, 4);       // spmm blocks per graph

  // embed (independent of CSR build)
  embed_gemm_relu<<<blocks(n / 4, 4), 256, 0, stream>>>(x, w_embed, r0, r0h,
                                                        n / 4);

  // CSR build: bucketize(+sharded rank) -> shard-merge scan -> rank-scatter
  hipMemsetAsync(cnt81, 0, ((size_t)16 * n + 128 * CPAD) * sizeof(int), stream);
  bucketize2<<<PA1 + PA2, 256, 0, stream>>>(
      a1_idx, a1_val, E1, cnt81, scur, bkt1, sub1, a2_idx, a2_val, E2, cnt82,
      scur + 64 * CPAD, bkt2, sub2, PA1, PA1 + PA2, invchunk, n);
  scan_blocks2<<<2 * NB, 512, 0, stream>>>(cnt81, rs1, aux1, so1, cnt82, rs2,
                                           aux2, so2, n, NB);
  scan_aux2<<<2, 512, 0, stream>>>(aux1, aux2, NB);
  add_offsets2<<<2 * NB, 512, 0, stream>>>(rs1, aux1, E1, rs2, aux2, E2, n, NB);
  build_epack2<<<PB1 + PB2, 256, 0, stream>>>(
      scur, bkt1, sub1, rs1, so1, ep1, scur + 64 * CPAD, bkt2, sub2, rs2, so2,
      ep2, PB1, PB1 + PB2);

  // hop 1: r0h -> r1 [n,128] f32 + r1h f16  (ReLU fused)
  spmm_h1<<<2 * SB, 256, 0, stream>>>(rs1, ep1, rs2, ep2, r0h, r1, r1h, n, SB);
  // hop 2: r1h -> r2 [n,256] f32  (ReLU fused)
  spmm_h2<<<2 * SB, 256, 0, stream>>>(rs1, ep1, rs2, ep2, r1h, r2, n, SB);

  classify_softmax<<<blocks(n, 4), 256, 0, stream>>>(r0, r1, r2, w_classify,
                                                     out, n);
}

// Round 12
// 475.559 us; speedup vs baseline: 1.0906x; 1.0906x over previous
//
#include <hip/hip_runtime.h>
#include <hip/hip_bf16.h>
#include <hip/hip_fp16.h>

// H2GCN inference:
//   r0 = relu(x @ w_embed)                       [N,64]
//   r1 = relu([spmm(a1,r0) | spmm(a2,r0)])       [N,128]
//   r2 = relu([spmm(a1,r1) | spmm(a2,r1)])       [N,256]
//   out = softmax([r0|r1|r2] @ w_classify)       [N,16]
//
// Round-12: CSR build = LDS counting sort, ZERO per-edge global atomics.
// r11 evidence: 2.4M returning atomics on cnt8 cost ~100us (WRITE 28->103MB
// = counter-line eviction thrash between streamed edges). New pipeline:
//   bucketize: ballot-append (row|col<<16, f16val) into 8 row-range buckets
//     x 8 stripes (64B-padded cursors only, ~37K leader atomics).
//   count_stripes: block (g,s) streams stripe, 25KB LDS histogram, writes
//     cnt8[s][range g] NON-atomically (each (shard,row) written once).
//   scan: r11's shard-merge scan -> rs (row offsets) + so (shard offsets).
//   scatter_stripes: re-read stripe (L2-hot, g=blk&7 pins bucket to one
//     XCD), LDS cursors: pos = rs[row]+so[row,s]+cursor++ -> ep (4B/edge).
// Bucket routing uses exact integer row/chunk (float recip boundary error
// would OOB the LDS histogram).

#define F_IN 256
#define H_DIM 64
#define CPAD 16      // ints per cursor (64B line)
#define MAXCHUNK 6272  // LDS histogram capacity (n/8 rows; n<=50176)

__device__ __forceinline__ unsigned short f2h(float x) {
  return __half_as_ushort(__float2half(x));
}
__device__ __forceinline__ float h2f(unsigned short u) {
  return __half2float(__ushort_as_half(u));
}

// ---------------- embed GEMM: r0 = relu(x @ w), + f16 mirror ----------
__global__ __launch_bounds__(256) void embed_gemm_relu(
    const float* __restrict__ x, const float* __restrict__ w,
    float* __restrict__ r0, unsigned short* __restrict__ r0h, int n_tiles) {
  __shared__ float ws[F_IN * H_DIM];  // 64 KB
  for (int i = threadIdx.x; i < F_IN * H_DIM / 4; i += 256)
    ((float4*)ws)[i] = ((const float4*)w)[i];
  __syncthreads();
  int lane = threadIdx.x & 63;
  int tile = blockIdx.x * 4 + (threadIdx.x >> 6);
  if (tile >= n_tiles) return;
  int row = tile * 4;
  float xv[4][4];
#pragma unroll
  for (int j = 0; j < 4; ++j)
#pragma unroll
    for (int q = 0; q < 4; ++q)
      xv[j][q] = x[(size_t)(row + j) * F_IN + q * 64 + lane];
  float acc[4] = {0.f, 0.f, 0.f, 0.f};
#pragma unroll
  for (int k = 0; k < 256; ++k) {
    float wk = ws[k * 64 + lane];
#pragma unroll
    for (int j = 0; j < 4; ++j) {
      float xb = __uint_as_float(
          __builtin_amdgcn_readlane(__float_as_uint(xv[j][k >> 6]), k & 63));
      acc[j] = fmaf(xb, wk, acc[j]);
    }
  }
#pragma unroll
  for (int j = 0; j < 4; ++j) {
    float v = fmaxf(acc[j], 0.f);
    r0[(size_t)(row + j) * H_DIM + lane] = v;
    r0h[(size_t)(row + j) * H_DIM + lane] = f2h(v);
  }
}

// ---------------- bucketize: wave-ballot append into 8x8 sub-buckets ----
// Payload: (row | col<<16, f16val). Cursors 64B-padded; stripe s = blk&7
// ~ XCD id -> cursor lines stay in one XCD's L2.
__global__ __launch_bounds__(256) void bucketize2(
    const int* __restrict__ i1, const float* __restrict__ v1, int E1,
    int* __restrict__ scur1, int2* __restrict__ bkt1, int sub1,
    const int* __restrict__ i2, const float* __restrict__ v2, int E2,
    int* __restrict__ scur2, int2* __restrict__ bkt2, int sub2, int PA1,
    int PAtot, int chunk) {
  int blk = blockIdx.x;
  const int* I;
  const float* V;
  int E, nb, sub;
  int* scur;
  int2* bkt;
  if (blk < PA1) {
    I = i1; V = v1; E = E1; scur = scur1; bkt = bkt1; sub = sub1; nb = PA1;
  } else {
    I = i2; V = v2; E = E2; scur = scur2; bkt = bkt2; sub = sub2;
    nb = PAtot - PA1; blk -= PA1;
  }
  int lane = threadIdx.x & 63;
  int s = blk & 7;  // stripe ~ XCD (round-robin dispatch heuristic)
  for (int base_i = blk * 256; base_i < E; base_i += nb * 256) {
    int i = base_i + threadIdx.x;
    bool valid = i < E;
    int row = 0, col = 0;
    float v = 0.f;
    if (valid) {
      row = I[i];
      col = I[E + i];
      v = V[i];
    }
    int mb = valid ? (int)((unsigned)row / (unsigned)chunk) : -1;  // exact
    int2 pk;
    pk.x = row | (col << 16);
    pk.y = (int)f2h(v);
#pragma unroll
    for (int b = 0; b < 8; ++b) {
      unsigned long long m = __ballot(mb == b);
      if (m) {
        int cnt = __popcll(m);
        int leader = __ffsll((long long)m) - 1;
        int base = 0;
        if (lane == leader) base = atomicAdd(&scur[(b * 8 + s) * CPAD], cnt);
        base = __shfl(base, leader, 64);
        if (mb == b) {
          int rank = __popcll(m & ((1ull << lane) - 1));
          bkt[(size_t)(b * 8 + s) * sub + base + rank] = pk;
        }
      }
    }
  }
}

// ---------------- count_stripes: LDS histogram, non-atomic cnt8 write ---
// blk: g = blk&7 (bucket/XCD), s = (blk>>3)&7 (stripe), graph = blk>>6.
__global__ __launch_bounds__(256) void count_stripes(
    const int* __restrict__ scur1, const int2* __restrict__ bkt1, int sub1,
    int* __restrict__ cnt81, const int* __restrict__ scur2,
    const int2* __restrict__ bkt2, int sub2, int* __restrict__ cnt82, int n,
    int chunk) {
  __shared__ int h[MAXCHUNK];
  int blk = blockIdx.x;
  int g = blk & 7;
  int s = (blk >> 3) & 7;
  int graph = blk >> 6;
  const int* scur = graph ? scur2 : scur1;
  const int2* bkt = graph ? bkt2 : bkt1;
  int sub = graph ? sub2 : sub1;
  int* cnt8 = graph ? cnt82 : cnt81;
  int lo = g * chunk;
  int nrows = min(n - lo, chunk);
  for (int j = threadIdx.x; j < nrows; j += 256) h[j] = 0;
  __syncthreads();
  int len = scur[(g * 8 + s) * CPAD];
  const int2* bp = bkt + (size_t)(g * 8 + s) * sub;
  for (int i = threadIdx.x; i < len; i += 256)
    atomicAdd(&h[(bp[i].x & 0xFFFF) - lo], 1);
  __syncthreads();
  for (int j = threadIdx.x; j < nrows; j += 256)
    cnt8[(size_t)s * n + lo + j] = h[j];
}

// ---------------- scan: merge 8 shards/row + exclusive scan ------------
__global__ __launch_bounds__(512) void scan_blocks2(
    const int* __restrict__ c81, int* __restrict__ e1, int* __restrict__ a1,
    unsigned short* __restrict__ so1, const int* __restrict__ c82,
    int* __restrict__ e2, int* __restrict__ a2,
    unsigned short* __restrict__ so2, int n, int NB) {
  const int* c8;
  int* exc;
  int* aux;
  unsigned short* so;
  int blk = blockIdx.x;
  if (blk < NB) {
    c8 = c81; exc = e1; aux = a1; so = so1;
  } else {
    c8 = c82; exc = e2; aux = a2; so = so2; blk -= NB;
  }
  __shared__ int tmp[512];
  int i = blk * 512 + threadIdx.x;
  int v = 0;
  if (i < n) {
    int acc = 0;
    unsigned off[8];
#pragma unroll
    for (int sh = 0; sh < 8; ++sh) {
      off[sh] = (unsigned)acc;
      acc += c8[(size_t)sh * n + i];
    }
    v = acc;
    uint4 st;
    st.x = off[0] | (off[1] << 16);
    st.y = off[2] | (off[3] << 16);
    st.z = off[4] | (off[5] << 16);
    st.w = off[6] | (off[7] << 16);
    *(uint4*)&so[(size_t)i * 8] = st;
  }
  tmp[threadIdx.x] = v;
  __syncthreads();
#pragma unroll
  for (int d = 1; d < 512; d <<= 1) {
    int t = (threadIdx.x >= d) ? tmp[threadIdx.x - d] : 0;
    __syncthreads();
    tmp[threadIdx.x] += t;
    __syncthreads();
  }
  if (i < n) exc[i] = tmp[threadIdx.x] - v;
  if (threadIdx.x == 511) aux[blk] = tmp[511];
}

__global__ __launch_bounds__(512) void scan_aux2(int* __restrict__ a1,
                                                 int* __restrict__ a2,
                                                 int nblk) {
  int* aux = (blockIdx.x == 0) ? a1 : a2;
  __shared__ int tmp[512];
  int v = (threadIdx.x < nblk) ? aux[threadIdx.x] : 0;
  tmp[threadIdx.x] = v;
  __syncthreads();
#pragma unroll
  for (int d = 1; d < 512; d <<= 1) {
    int t = (threadIdx.x >= d) ? tmp[threadIdx.x - d] : 0;
    __syncthreads();
    tmp[threadIdx.x] += t;
    __syncthreads();
  }
  if (threadIdx.x < nblk) aux[threadIdx.x] = tmp[threadIdx.x] - v;
}

__global__ __launch_bounds__(512) void add_offsets2(
    int* __restrict__ rs1, const int* __restrict__ a1, int E1,
    int* __restrict__ rs2, const int* __restrict__ a2, int E2, int n, int NB) {
  int blk = blockIdx.x;
  int* rs;
  const int* aux;
  int E;
  if (blk < NB) {
    rs = rs1; aux = a1; E = E1;
  } else {
    rs = rs2; aux = a2; E = E2; blk -= NB;
  }
  int i = blk * 512 + threadIdx.x;
  if (i < n) rs[i] += aux[blk];
  if (blk == 0 && threadIdx.x == 0) rs[n] = E;
}

// ---------------- scatter_stripes: LDS cursors, no global atomics ------
__global__ __launch_bounds__(256) void scatter_stripes(
    const int* __restrict__ scur1, const int2* __restrict__ bkt1, int sub1,
    const int* __restrict__ rs1, const unsigned short* __restrict__ so1,
    unsigned* __restrict__ ep1, const int* __restrict__ scur2,
    const int2* __restrict__ bkt2, int sub2, const int* __restrict__ rs2,
    const unsigned short* __restrict__ so2, unsigned* __restrict__ ep2,
    int n, int chunk) {
  __shared__ int h[MAXCHUNK];
  int blk = blockIdx.x;
  int g = blk & 7;
  int s = (blk >> 3) & 7;
  int graph = blk >> 6;
  const int* scur = graph ? scur2 : scur1;
  const int2* bkt = graph ? bkt2 : bkt1;
  int sub = graph ? sub2 : sub1;
  const int* rs = graph ? rs2 : rs1;
  const unsigned short* so = graph ? so2 : so1;
  unsigned* ep = graph ? ep2 : ep1;
  int lo = g * chunk;
  int nrows = min(n - lo, chunk);
  for (int j = threadIdx.x; j < nrows; j += 256) h[j] = 0;
  __syncthreads();
  int len = scur[(g * 8 + s) * CPAD];
  const int2* bp = bkt + (size_t)(g * 8 + s) * sub;
  for (int i = threadIdx.x; i < len; i += 256) {
    int2 e = bp[i];
    int row = e.x & 0xFFFF;
    unsigned col = (unsigned)e.x >> 16;
    int lr = atomicAdd(&h[row - lo], 1);  // LDS atomic
    int p = rs[row] + (int)so[(size_t)row * 8 + s] + lr;
    ep[p] = ((unsigned)(e.y & 0xFFFF) << 16) | col;
  }
}

// ---------------- hop1: r0h (f16,[n,64]) -> r1 f32 + r1h f16 ----------
__global__ __launch_bounds__(256) void spmm_h1(
    const int* __restrict__ rs1, const unsigned* __restrict__ ep1,
    const int* __restrict__ rs2, const unsigned* __restrict__ ep2,
    const unsigned short* __restrict__ r0h, float* __restrict__ r1,
    unsigned short* __restrict__ r1h, int n, int SB) {
  const int* rs;
  const unsigned* epack;
  int coff;
  int blk = blockIdx.x;
  if (blk < SB) {
    rs = rs1; epack = ep1; coff = 0;
  } else {
    rs = rs2; epack = ep2; coff = 64; blk -= SB;
  }
  int lane = threadIdx.x & 63;
  int row = blk * 4 + (threadIdx.x >> 6);
  if (row >= n) return;
  int s = rs[row], e = rs[row + 1];
  float acc = 0.f;
  int j = s;
  for (; j + 8 <= e; j += 8) {
    unsigned pk[8];
#pragma unroll
    for (int u = 0; u < 8; ++u) pk[u] = epack[j + u];
    float xg[8];
#pragma unroll
    for (int u = 0; u < 8; ++u)
      xg[u] = h2f(r0h[(size_t)(pk[u] & 0xFFFF) * 64 + lane]);
#pragma unroll
    for (int u = 0; u < 8; ++u)
      acc = fmaf(h2f((unsigned short)(pk[u] >> 16)), xg[u], acc);
  }
  for (; j < e; ++j) {
    unsigned pk = epack[j];
    acc = fmaf(h2f((unsigned short)(pk >> 16)),
               h2f(r0h[(size_t)(pk & 0xFFFF) * 64 + lane]), acc);
  }
  float v = fmaxf(acc, 0.f);
  r1[(size_t)row * 128 + coff + lane] = v;
  r1h[(size_t)row * 128 + coff + lane] = f2h(v);
}

// ---------------- hop2: r1h (f16,[n,128]) -> r2 f32 -------------------
__global__ __launch_bounds__(256) void spmm_h2(
    const int* __restrict__ rs1, const unsigned* __restrict__ ep1,
    const int* __restrict__ rs2, const unsigned* __restrict__ ep2,
    const unsigned short* __restrict__ r1h, float* __restrict__ r2, int n,
    int SB) {
  const int* rs;
  const unsigned* epack;
  int coff;
  int blk = blockIdx.x;
  if (blk < SB) {
    rs = rs1; epack = ep1; coff = 0;
  } else {
    rs = rs2; epack = ep2; coff = 128; blk -= SB;
  }
  int lane = threadIdx.x & 63;
  int row = blk * 4 + (threadIdx.x >> 6);
  if (row >= n) return;
  int s = rs[row], e = rs[row + 1];
  float acc0 = 0.f, acc1 = 0.f;
  int j = s;
  for (; j + 8 <= e; j += 8) {
    unsigned pk[8];
#pragma unroll
    for (int u = 0; u < 8; ++u) pk[u] = epack[j + u];
    unsigned g[8];
#pragma unroll
    for (int u = 0; u < 8; ++u)
      g[u] = *(const unsigned*)&r1h[(size_t)(pk[u] & 0xFFFF) * 128 + lane * 2];
#pragma unroll
    for (int u = 0; u < 8; ++u) {
      float v = h2f((unsigned short)(pk[u] >> 16));
      acc0 = fmaf(v, h2f((unsigned short)(g[u] & 0xFFFF)), acc0);
      acc1 = fmaf(v, h2f((unsigned short)(g[u] >> 16)), acc1);
    }
  }
  for (; j < e; ++j) {
    unsigned pk = epack[j];
    unsigned g = *(const unsigned*)&r1h[(size_t)(pk & 0xFFFF) * 128 + lane * 2];
    float v = h2f((unsigned short)(pk >> 16));
    acc0 = fmaf(v, h2f((unsigned short)(g & 0xFFFF)), acc0);
    acc1 = fmaf(v, h2f((unsigned short)(g >> 16)), acc1);
  }
  float2 st;
  st.x = fmaxf(acc0, 0.f);
  st.y = fmaxf(acc1, 0.f);
  *(float2*)&r2[(size_t)row * 256 + coff + lane * 2] = st;
}

// ---------------- classifier + softmax --------------------------------
__global__ __launch_bounds__(256) void classify_softmax(
    const float* __restrict__ r0, const float* __restrict__ r1,
    const float* __restrict__ r2, const float* __restrict__ wc,
    float* __restrict__ out, int n) {
  __shared__ float wls[448 * 17];  // stride 17: no bank conflict
  for (int i = threadIdx.x; i < 448 * 16; i += 256)
    wls[(i >> 4) * 17 + (i & 15)] = wc[i];
  __syncthreads();
  int lane = threadIdx.x & 63;
  int c = lane & 15;
  int part = lane >> 4;
  int node = blockIdx.x * 4 + (threadIdx.x >> 6);
  if (node >= n) return;

  float acc = 0.f;
  {
    const float* p = r0 + (size_t)node * 64 + part * 16;
#pragma unroll
    for (int j = 0; j < 4; ++j) {
      float4 rv = *(const float4*)(p + 4 * j);
      int fb = part * 16 + 4 * j;
      acc = fmaf(rv.x, wls[(fb + 0) * 17 + c], acc);
      acc = fmaf(rv.y, wls[(fb + 1) * 17 + c], acc);
      acc = fmaf(rv.z, wls[(fb + 2) * 17 + c], acc);
      acc = fmaf(rv.w, wls[(fb + 3) * 17 + c], acc);
    }
  }
  {
    const float* p = r1 + (size_t)node * 128 + part * 32;
#pragma unroll
    for (int j = 0; j < 8; ++j) {
      float4 rv = *(const float4*)(p + 4 * j);
      int fb = 64 + part * 32 + 4 * j;
      acc = fmaf(rv.x, wls[(fb + 0) * 17 + c], acc);
      acc = fmaf(rv.y, wls[(fb + 1) * 17 + c], acc);
      acc = fmaf(rv.z, wls[(fb + 2) * 17 + c], acc);
      acc = fmaf(rv.w, wls[(fb + 3) * 17 + c], acc);
    }
  }
  {
    const float* p = r2 + (size_t)node * 256 + part * 64;
#pragma unroll
    for (int j = 0; j < 16; ++j) {
      float4 rv = *(const float4*)(p + 4 * j);
      int fb = 192 + part * 64 + 4 * j;
      acc = fmaf(rv.x, wls[(fb + 0) * 17 + c], acc);
      acc = fmaf(rv.y, wls[(fb + 1) * 17 + c], acc);
      acc = fmaf(rv.z, wls[(fb + 2) * 17 + c], acc);
      acc = fmaf(rv.w, wls[(fb + 3) * 17 + c], acc);
    }
  }
  acc += __shfl_xor(acc, 16, 64);
  acc += __shfl_xor(acc, 32, 64);
  float m = acc;
#pragma unroll
  for (int d = 1; d < 16; d <<= 1) m = fmaxf(m, __shfl_xor(m, d, 64));
  float ex = __expf(acc - m);
  float s = ex;
#pragma unroll
  for (int d = 1; d < 16; d <<= 1) s += __shfl_xor(s, d, 64);
  if (lane < 16) out[(size_t)node * 16 + c] = ex / s;
}

extern "C" void kernel_launch(void* const* d_in, const int* in_sizes, int n_in,
                              void* d_out, int out_size, void* d_ws, size_t ws_size,
                              hipStream_t stream) {
  const float* x = (const float*)d_in[0];
  const int* a1_idx = (const int*)d_in[1];
  const float* a1_val = (const float*)d_in[2];
  const int* a2_idx = (const int*)d_in[3];
  const float* a2_val = (const float*)d_in[4];
  const float* w_embed = (const float*)d_in[5];
  const float* w_classify = (const float*)d_in[6];
  float* out = (float*)d_out;

  const int n = in_sizes[0] / F_IN;  // 50000 (< 65536: u16 row/col packing)
  const int E1 = in_sizes[2];        // 800000
  const int E2 = in_sizes[4];        // 1600000
  const int chunk = (n + 7) / 8;     // 6250 rows per bucket (<= MAXCHUNK)
  const int sub1 = E1 / 64 + 4096;   // sub-bucket capacity (8 buckets x 8)
  const int sub2 = E2 / 64 + 4096;

  // workspace layout (sizes kept multiples of 4 ints for 16B alignment)
  float* r0 = (float*)d_ws;                        // n*64 f32
  float* r1 = r0 + (size_t)n * 64;                 // n*128 f32
  float* r2 = r1 + (size_t)n * 128;                // n*256 f32
  unsigned short* r0h = (unsigned short*)(r2 + (size_t)n * 256);  // n*64
  unsigned short* r1h = r0h + (size_t)n * 64;      // n*128
  int* cnt81 = (int*)(r1h + (size_t)n * 128);      // 8n
  int* cnt82 = cnt81 + (size_t)8 * n;              // 8n
  int* scur = cnt82 + (size_t)8 * n;               // 128 cursors x CPAD
  int* rs1 = scur + 128 * CPAD;                    // n+4
  int* rs2 = rs1 + (n + 4);                        // n+4
  int* aux1 = rs2 + (n + 4);                       // 512
  int* aux2 = aux1 + 512;                          // 512
  unsigned short* so1 = (unsigned short*)(aux2 + 512);  // 8n u16
  unsigned short* so2 = so1 + (size_t)8 * n;       // 8n u16
  unsigned* ep1 = (unsigned*)(so2 + (size_t)8 * n);  // E1 (4B/edge)
  unsigned* ep2 = ep1 + E1;                        // E2
  // buckets ALIAS r2 (dead until spmm_h2 writes r2): 23.4MB <= 51.2MB
  int2* bkt1 = (int2*)r2;                          // 64*sub1 entries
  int2* bkt2 = bkt1 + (size_t)64 * sub1;           // 64*sub2 entries

  auto blocks = [](long long t, int bs) { return (int)((t + bs - 1) / bs); };
  const int NB = blocks(n, 512);     // 98
  const int PA1 = 1024, PA2 = 2048;  // bucketize blocks (mult of 8)
  const int SB = blocks(n, 4);       // spmm blocks per graph

  // embed (independent of CSR build)
  embed_gemm_relu<<<blocks(n / 4, 4), 256, 0, stream>>>(x, w_embed, r0, r0h,
                                                        n / 4);

  // CSR build: bucketize -> LDS count -> shard-merge scan -> LDS scatter
  hipMemsetAsync(scur, 0, 128 * CPAD * sizeof(int), stream);
  bucketize2<<<PA1 + PA2, 256, 0, stream>>>(
      a1_idx, a1_val, E1, scur, bkt1, sub1, a2_idx, a2_val, E2,
      scur + 64 * CPAD, bkt2, sub2, PA1, PA1 + PA2, chunk);
  count_stripes<<<128, 256, 0, stream>>>(scur, bkt1, sub1, cnt81,
                                         scur + 64 * CPAD, bkt2, sub2, cnt82,
                                         n, chunk);
  scan_blocks2<<<2 * NB, 512, 0, stream>>>(cnt81, rs1, aux1, so1, cnt82, rs2,
                                           aux2, so2, n, NB);
  scan_aux2<<<2, 512, 0, stream>>>(aux1, aux2, NB);
  add_offsets2<<<2 * NB, 512, 0, stream>>>(rs1, aux1, E1, rs2, aux2, E2, n, NB);
  scatter_stripes<<<128, 256, 0, stream>>>(
      scur, bkt1, sub1, rs1, so1, ep1, scur + 64 * CPAD, bkt2, sub2, rs2, so2,
      ep2, n, chunk);

  // hop 1: r0h -> r1 [n,128] f32 + r1h f16  (ReLU fused)
  spmm_h1<<<2 * SB, 256, 0, stream>>>(rs1, ep1, rs2, ep2, r0h, r1, r1h, n, SB);
  // hop 2: r1h -> r2 [n,256] f32  (ReLU fused)
  spmm_h2<<<2 * SB, 256, 0, stream>>>(rs1, ep1, rs2, ep2, r1h, r2, n, SB);

  classify_softmax<<<blocks(n, 4), 256, 0, stream>>>(r0, r1, r2, w_classify,
                                                     out, n);
}

// Round 13
// 462.229 us; speedup vs baseline: 1.1221x; 1.0288x over previous
//
#include <hip/hip_runtime.h>
#include <hip/hip_bf16.h>
#include <hip/hip_fp16.h>

// H2GCN inference:
//   r0 = relu(x @ w_embed)                       [N,64]
//   r1 = relu([spmm(a1,r0) | spmm(a2,r0)])       [N,128]
//   r2 = relu([spmm(a1,r1) | spmm(a2,r1)])       [N,256]
//   out = softmax([r0|r1|r2] @ w_classify)       [N,16]
//
// Round-13: r12 pipeline (LDS counting-sort CSR build, zero per-edge
// global atomics) + bucketize ballot-loop ROTATION. r12 counters:
// bucketize2 89us, VALUBusy 12%, HBM 6% -> same-line atomic convoy: all
// waves swept cursors in the same b=0..7 order, concentrating ~12K waves'
// leader-atomics on ONE cursor line at a time. Fix: b = (bb + wave_id)&7
// spreads concurrent atomics across all 8 lines (8x effective throughput).

#define F_IN 256
#define H_DIM 64
#define CPAD 16      // ints per cursor (64B line)
#define MAXCHUNK 6272  // LDS histogram capacity (n/8 rows; n<=50176)

__device__ __forceinline__ unsigned short f2h(float x) {
  return __half_as_ushort(__float2half(x));
}
__device__ __forceinline__ float h2f(unsigned short u) {
  return __half2float(__ushort_as_half(u));
}

// ---------------- embed GEMM: r0 = relu(x @ w), + f16 mirror ----------
__global__ __launch_bounds__(256) void embed_gemm_relu(
    const float* __restrict__ x, const float* __restrict__ w,
    float* __restrict__ r0, unsigned short* __restrict__ r0h, int n_tiles) {
  __shared__ float ws[F_IN * H_DIM];  // 64 KB
  for (int i = threadIdx.x; i < F_IN * H_DIM / 4; i += 256)
    ((float4*)ws)[i] = ((const float4*)w)[i];
  __syncthreads();
  int lane = threadIdx.x & 63;
  int tile = blockIdx.x * 4 + (threadIdx.x >> 6);
  if (tile >= n_tiles) return;
  int row = tile * 4;
  float xv[4][4];
#pragma unroll
  for (int j = 0; j < 4; ++j)
#pragma unroll
    for (int q = 0; q < 4; ++q)
      xv[j][q] = x[(size_t)(row + j) * F_IN + q * 64 + lane];
  float acc[4] = {0.f, 0.f, 0.f, 0.f};
#pragma unroll
  for (int k = 0; k < 256; ++k) {
    float wk = ws[k * 64 + lane];
#pragma unroll
    for (int j = 0; j < 4; ++j) {
      float xb = __uint_as_float(
          __builtin_amdgcn_readlane(__float_as_uint(xv[j][k >> 6]), k & 63));
      acc[j] = fmaf(xb, wk, acc[j]);
    }
  }
#pragma unroll
  for (int j = 0; j < 4; ++j) {
    float v = fmaxf(acc[j], 0.f);
    r0[(size_t)(row + j) * H_DIM + lane] = v;
    r0h[(size_t)(row + j) * H_DIM + lane] = f2h(v);
  }
}

// ---------------- bucketize: wave-ballot append into 8x8 sub-buckets ----
// Payload: (row | col<<16, f16val). Cursors 64B-padded; stripe s = blk&7
// ~ XCD id -> cursor lines stay in one XCD's L2. Bucket sweep ROTATED per
// wave so concurrent leader-atomics spread across all 8 cursor lines.
__global__ __launch_bounds__(256) void bucketize2(
    const int* __restrict__ i1, const float* __restrict__ v1, int E1,
    int* __restrict__ scur1, int2* __restrict__ bkt1, int sub1,
    const int* __restrict__ i2, const float* __restrict__ v2, int E2,
    int* __restrict__ scur2, int2* __restrict__ bkt2, int sub2, int PA1,
    int PAtot, int chunk) {
  int blk = blockIdx.x;
  const int* I;
  const float* V;
  int E, nb, sub;
  int* scur;
  int2* bkt;
  if (blk < PA1) {
    I = i1; V = v1; E = E1; scur = scur1; bkt = bkt1; sub = sub1; nb = PA1;
  } else {
    I = i2; V = v2; E = E2; scur = scur2; bkt = bkt2; sub = sub2;
    nb = PAtot - PA1; blk -= PA1;
  }
  int lane = threadIdx.x & 63;
  int s = blk & 7;  // stripe ~ XCD (round-robin dispatch heuristic)
  int wrot = ((blk << 2) + (threadIdx.x >> 6)) & 7;  // per-wave rotation
  for (int base_i = blk * 256; base_i < E; base_i += nb * 256) {
    int i = base_i + threadIdx.x;
    bool valid = i < E;
    int row = 0, col = 0;
    float v = 0.f;
    if (valid) {
      row = I[i];
      col = I[E + i];
      v = V[i];
    }
    int mb = valid ? (int)((unsigned)row / (unsigned)chunk) : -1;  // exact
    int2 pk;
    pk.x = row | (col << 16);
    pk.y = (int)f2h(v);
#pragma unroll
    for (int bb = 0; bb < 8; ++bb) {
      int b = (bb + wrot) & 7;  // rotated sweep -> decontended cursors
      unsigned long long m = __ballot(mb == b);
      if (m) {
        int cnt = __popcll(m);
        int leader = __ffsll((long long)m) - 1;
        int base = 0;
        if (lane == leader) base = atomicAdd(&scur[(b * 8 + s) * CPAD], cnt);
        base = __shfl(base, leader, 64);
        if (mb == b) {
          int rank = __popcll(m & ((1ull << lane) - 1));
          bkt[(size_t)(b * 8 + s) * sub + base + rank] = pk;
        }
      }
    }
  }
}

// ---------------- count_stripes: LDS histogram, non-atomic cnt8 write ---
// blk: g = blk&7 (bucket/XCD), s = (blk>>3)&7 (stripe), graph = blk>>6.
__global__ __launch_bounds__(256) void count_stripes(
    const int* __restrict__ scur1, const int2* __restrict__ bkt1, int sub1,
    int* __restrict__ cnt81, const int* __restrict__ scur2,
    const int2* __restrict__ bkt2, int sub2, int* __restrict__ cnt82, int n,
    int chunk) {
  __shared__ int h[MAXCHUNK];
  int blk = blockIdx.x;
  int g = blk & 7;
  int s = (blk >> 3) & 7;
  int graph = blk >> 6;
  const int* scur = graph ? scur2 : scur1;
  const int2* bkt = graph ? bkt2 : bkt1;
  int sub = graph ? sub2 : sub1;
  int* cnt8 = graph ? cnt82 : cnt81;
  int lo = g * chunk;
  int nrows = min(n - lo, chunk);
  for (int j = threadIdx.x; j < nrows; j += 256) h[j] = 0;
  __syncthreads();
  int len = scur[(g * 8 + s) * CPAD];
  const int2* bp = bkt + (size_t)(g * 8 + s) * sub;
  for (int i = threadIdx.x; i < len; i += 256)
    atomicAdd(&h[(bp[i].x & 0xFFFF) - lo], 1);
  __syncthreads();
  for (int j = threadIdx.x; j < nrows; j += 256)
    cnt8[(size_t)s * n + lo + j] = h[j];
}

// ---------------- scan: merge 8 shards/row + exclusive scan ------------
__global__ __launch_bounds__(512) void scan_blocks2(
    const int* __restrict__ c81, int* __restrict__ e1, int* __restrict__ a1,
    unsigned short* __restrict__ so1, const int* __restrict__ c82,
    int* __restrict__ e2, int* __restrict__ a2,
    unsigned short* __restrict__ so2, int n, int NB) {
  const int* c8;
  int* exc;
  int* aux;
  unsigned short* so;
  int blk = blockIdx.x;
  if (blk < NB) {
    c8 = c81; exc = e1; aux = a1; so = so1;
  } else {
    c8 = c82; exc = e2; aux = a2; so = so2; blk -= NB;
  }
  __shared__ int tmp[512];
  int i = blk * 512 + threadIdx.x;
  int v = 0;
  if (i < n) {
    int acc = 0;
    unsigned off[8];
#pragma unroll
    for (int sh = 0; sh < 8; ++sh) {
      off[sh] = (unsigned)acc;
      acc += c8[(size_t)sh * n + i];
    }
    v = acc;
    uint4 st;
    st.x = off[0] | (off[1] << 16);
    st.y = off[2] | (off[3] << 16);
    st.z = off[4] | (off[5] << 16);
    st.w = off[6] | (off[7] << 16);
    *(uint4*)&so[(size_t)i * 8] = st;
  }
  tmp[threadIdx.x] = v;
  __syncthreads();
#pragma unroll
  for (int d = 1; d < 512; d <<= 1) {
    int t = (threadIdx.x >= d) ? tmp[threadIdx.x - d] : 0;
    __syncthreads();
    tmp[threadIdx.x] += t;
    __syncthreads();
  }
  if (i < n) exc[i] = tmp[threadIdx.x] - v;
  if (threadIdx.x == 511) aux[blk] = tmp[511];
}

__global__ __launch_bounds__(512) void scan_aux2(int* __restrict__ a1,
                                                 int* __restrict__ a2,
                                                 int nblk) {
  int* aux = (blockIdx.x == 0) ? a1 : a2;
  __shared__ int tmp[512];
  int v = (threadIdx.x < nblk) ? aux[threadIdx.x] : 0;
  tmp[threadIdx.x] = v;
  __syncthreads();
#pragma unroll
  for (int d = 1; d < 512; d <<= 1) {
    int t = (threadIdx.x >= d) ? tmp[threadIdx.x - d] : 0;
    __syncthreads();
    tmp[threadIdx.x] += t;
    __syncthreads();
  }
  if (threadIdx.x < nblk) aux[threadIdx.x] = tmp[threadIdx.x] - v;
}

__global__ __launch_bounds__(512) void add_offsets2(
    int* __restrict__ rs1, const int* __restrict__ a1, int E1,
    int* __restrict__ rs2, const int* __restrict__ a2, int E2, int n, int NB) {
  int blk = blockIdx.x;
  int* rs;
  const int* aux;
  int E;
  if (blk < NB) {
    rs = rs1; aux = a1; E = E1;
  } else {
    rs = rs2; aux = a2; E = E2; blk -= NB;
  }
  int i = blk * 512 + threadIdx.x;
  if (i < n) rs[i] += aux[blk];
  if (blk == 0 && threadIdx.x == 0) rs[n] = E;
}

// ---------------- scatter_stripes: LDS cursors, no global atomics ------
__global__ __launch_bounds__(256) void scatter_stripes(
    const int* __restrict__ scur1, const int2* __restrict__ bkt1, int sub1,
    const int* __restrict__ rs1, const unsigned short* __restrict__ so1,
    unsigned* __restrict__ ep1, const int* __restrict__ scur2,
    const int2* __restrict__ bkt2, int sub2, const int* __restrict__ rs2,
    const unsigned short* __restrict__ so2, unsigned* __restrict__ ep2,
    int n, int chunk) {
  __shared__ int h[MAXCHUNK];
  int blk = blockIdx.x;
  int g = blk & 7;
  int s = (blk >> 3) & 7;
  int graph = blk >> 6;
  const int* scur = graph ? scur2 : scur1;
  const int2* bkt = graph ? bkt2 : bkt1;
  int sub = graph ? sub2 : sub1;
  const int* rs = graph ? rs2 : rs1;
  const unsigned short* so = graph ? so2 : so1;
  unsigned* ep = graph ? ep2 : ep1;
  int lo = g * chunk;
  int nrows = min(n - lo, chunk);
  for (int j = threadIdx.x; j < nrows; j += 256) h[j] = 0;
  __syncthreads();
  int len = scur[(g * 8 + s) * CPAD];
  const int2* bp = bkt + (size_t)(g * 8 + s) * sub;
  for (int i = threadIdx.x; i < len; i += 256) {
    int2 e = bp[i];
    int row = e.x & 0xFFFF;
    unsigned col = (unsigned)e.x >> 16;
    int lr = atomicAdd(&h[row - lo], 1);  // LDS atomic
    int p = rs[row] + (int)so[(size_t)row * 8 + s] + lr;
    ep[p] = ((unsigned)(e.y & 0xFFFF) << 16) | col;
  }
}

// ---------------- hop1: r0h (f16,[n,64]) -> r1 f32 + r1h f16 ----------
__global__ __launch_bounds__(256) void spmm_h1(
    const int* __restrict__ rs1, const unsigned* __restrict__ ep1,
    const int* __restrict__ rs2, const unsigned* __restrict__ ep2,
    const unsigned short* __restrict__ r0h, float* __restrict__ r1,
    unsigned short* __restrict__ r1h, int n, int SB) {
  const int* rs;
  const unsigned* epack;
  int coff;
  int blk = blockIdx.x;
  if (blk < SB) {
    rs = rs1; epack = ep1; coff = 0;
  } else {
    rs = rs2; epack = ep2; coff = 64; blk -= SB;
  }
  int lane = threadIdx.x & 63;
  int row = blk * 4 + (threadIdx.x >> 6);
  if (row >= n) return;
  int s = rs[row], e = rs[row + 1];
  float acc = 0.f;
  int j = s;
  for (; j + 8 <= e; j += 8) {
    unsigned pk[8];
#pragma unroll
    for (int u = 0; u < 8; ++u) pk[u] = epack[j + u];
    float xg[8];
#pragma unroll
    for (int u = 0; u < 8; ++u)
      xg[u] = h2f(r0h[(size_t)(pk[u] & 0xFFFF) * 64 + lane]);
#pragma unroll
    for (int u = 0; u < 8; ++u)
      acc = fmaf(h2f((unsigned short)(pk[u] >> 16)), xg[u], acc);
  }
  for (; j < e; ++j) {
    unsigned pk = epack[j];
    acc = fmaf(h2f((unsigned short)(pk >> 16)),
               h2f(r0h[(size_t)(pk & 0xFFFF) * 64 + lane]), acc);
  }
  float v = fmaxf(acc, 0.f);
  r1[(size_t)row * 128 + coff + lane] = v;
  r1h[(size_t)row * 128 + coff + lane] = f2h(v);
}

// ---------------- hop2: r1h (f16,[n,128]) -> r2 f32 -------------------
__global__ __launch_bounds__(256) void spmm_h2(
    const int* __restrict__ rs1, const unsigned* __restrict__ ep1,
    const int* __restrict__ rs2, const unsigned* __restrict__ ep2,
    const unsigned short* __restrict__ r1h, float* __restrict__ r2, int n,
    int SB) {
  const int* rs;
  const unsigned* epack;
  int coff;
  int blk = blockIdx.x;
  if (blk < SB) {
    rs = rs1; epack = ep1; coff = 0;
  } else {
    rs = rs2; epack = ep2; coff = 128; blk -= SB;
  }
  int lane = threadIdx.x & 63;
  int row = blk * 4 + (threadIdx.x >> 6);
  if (row >= n) return;
  int s = rs[row], e = rs[row + 1];
  float acc0 = 0.f, acc1 = 0.f;
  int j = s;
  for (; j + 8 <= e; j += 8) {
    unsigned pk[8];
#pragma unroll
    for (int u = 0; u < 8; ++u) pk[u] = epack[j + u];
    unsigned g[8];
#pragma unroll
    for (int u = 0; u < 8; ++u)
      g[u] = *(const unsigned*)&r1h[(size_t)(pk[u] & 0xFFFF) * 128 + lane * 2];
#pragma unroll
    for (int u = 0; u < 8; ++u) {
      float v = h2f((unsigned short)(pk[u] >> 16));
      acc0 = fmaf(v, h2f((unsigned short)(g[u] & 0xFFFF)), acc0);
      acc1 = fmaf(v, h2f((unsigned short)(g[u] >> 16)), acc1);
    }
  }
  for (; j < e; ++j) {
    unsigned pk = epack[j];
    unsigned g = *(const unsigned*)&r1h[(size_t)(pk & 0xFFFF) * 128 + lane * 2];
    float v = h2f((unsigned short)(pk >> 16));
    acc0 = fmaf(v, h2f((unsigned short)(g & 0xFFFF)), acc0);
    acc1 = fmaf(v, h2f((unsigned short)(g >> 16)), acc1);
  }
  float2 st;
  st.x = fmaxf(acc0, 0.f);
  st.y = fmaxf(acc1, 0.f);
  *(float2*)&r2[(size_t)row * 256 + coff + lane * 2] = st;
}

// ---------------- classifier + softmax --------------------------------
__global__ __launch_bounds__(256) void classify_softmax(
    const float* __restrict__ r0, const float* __restrict__ r1,
    const float* __restrict__ r2, const float* __restrict__ wc,
    float* __restrict__ out, int n) {
  __shared__ float wls[448 * 17];  // stride 17: no bank conflict
  for (int i = threadIdx.x; i < 448 * 16; i += 256)
    wls[(i >> 4) * 17 + (i & 15)] = wc[i];
  __syncthreads();
  int lane = threadIdx.x & 63;
  int c = lane & 15;
  int part = lane >> 4;
  int node = blockIdx.x * 4 + (threadIdx.x >> 6);
  if (node >= n) return;

  float acc = 0.f;
  {
    const float* p = r0 + (size_t)node * 64 + part * 16;
#pragma unroll
    for (int j = 0; j < 4; ++j) {
      float4 rv = *(const float4*)(p + 4 * j);
      int fb = part * 16 + 4 * j;
      acc = fmaf(rv.x, wls[(fb + 0) * 17 + c], acc);
      acc = fmaf(rv.y, wls[(fb + 1) * 17 + c], acc);
      acc = fmaf(rv.z, wls[(fb + 2) * 17 + c], acc);
      acc = fmaf(rv.w, wls[(fb + 3) * 17 + c], acc);
    }
  }
  {
    const float* p = r1 + (size_t)node * 128 + part * 32;
#pragma unroll
    for (int j = 0; j < 8; ++j) {
      float4 rv = *(const float4*)(p + 4 * j);
      int fb = 64 + part * 32 + 4 * j;
      acc = fmaf(rv.x, wls[(fb + 0) * 17 + c], acc);
      acc = fmaf(rv.y, wls[(fb + 1) * 17 + c], acc);
      acc = fmaf(rv.z, wls[(fb + 2) * 17 + c], acc);
      acc = fmaf(rv.w, wls[(fb + 3) * 17 + c], acc);
    }
  }
  {
    const float* p = r2 + (size_t)node * 256 + part * 64;
#pragma unroll
    for (int j = 0; j < 16; ++j) {
      float4 rv = *(const float4*)(p + 4 * j);
      int fb = 192 + part * 64 + 4 * j;
      acc = fmaf(rv.x, wls[(fb + 0) * 17 + c], acc);
      acc = fmaf(rv.y, wls[(fb + 1) * 17 + c], acc);
      acc = fmaf(rv.z, wls[(fb + 2) * 17 + c], acc);
      acc = fmaf(rv.w, wls[(fb + 3) * 17 + c], acc);
    }
  }
  acc += __shfl_xor(acc, 16, 64);
  acc += __shfl_xor(acc, 32, 64);
  float m = acc;
#pragma unroll
  for (int d = 1; d < 16; d <<= 1) m = fmaxf(m, __shfl_xor(m, d, 64));
  float ex = __expf(acc - m);
  float s = ex;
#pragma unroll
  for (int d = 1; d < 16; d <<= 1) s += __shfl_xor(s, d, 64);
  if (lane < 16) out[(size_t)node * 16 + c] = ex / s;
}

extern "C" void kernel_launch(void* const* d_in, const int* in_sizes, int n_in,
                              void* d_out, int out_size, void* d_ws, size_t ws_size,
                              hipStream_t stream) {
  const float* x = (const float*)d_in[0];
  const int* a1_idx = (const int*)d_in[1];
  const float* a1_val = (const float*)d_in[2];
  const int* a2_idx = (const int*)d_in[3];
  const float* a2_val = (const float*)d_in[4];
  const float* w_embed = (const float*)d_in[5];
  const float* w_classify = (const float*)d_in[6];
  float* out = (float*)d_out;

  const int n = in_sizes[0] / F_IN;  // 50000 (< 65536: u16 row/col packing)
  const int E1 = in_sizes[2];        // 800000
  const int E2 = in_sizes[4];        // 1600000
  const int chunk = (n + 7) / 8;     // 6250 rows per bucket (<= MAXCHUNK)
  const int sub1 = E1 / 64 + 4096;   // sub-bucket capacity (8 buckets x 8)
  const int sub2 = E2 / 64 + 4096;

  // workspace layout (sizes kept multiples of 4 ints for 16B alignment)
  float* r0 = (float*)d_ws;                        // n*64 f32
  float* r1 = r0 + (size_t)n * 64;                 // n*128 f32
  float* r2 = r1 + (size_t)n * 128;                // n*256 f32
  unsigned short* r0h = (unsigned short*)(r2 + (size_t)n * 256);  // n*64
  unsigned short* r1h = r0h + (size_t)n * 64;      // n*128
  int* cnt81 = (int*)(r1h + (size_t)n * 128);      // 8n
  int* cnt82 = cnt81 + (size_t)8 * n;              // 8n
  int* scur = cnt82 + (size_t)8 * n;               // 128 cursors x CPAD
  int* rs1 = scur + 128 * CPAD;                    // n+4
  int* rs2 = rs1 + (n + 4);                        // n+4
  int* aux1 = rs2 + (n + 4);                       // 512
  int* aux2 = aux1 + 512;                          // 512
  unsigned short* so1 = (unsigned short*)(aux2 + 512);  // 8n u16
  unsigned short* so2 = so1 + (size_t)8 * n;       // 8n u16
  unsigned* ep1 = (unsigned*)(so2 + (size_t)8 * n);  // E1 (4B/edge)
  unsigned* ep2 = ep1 + E1;                        // E2
  // buckets ALIAS r2 (dead until spmm_h2 writes r2): 23.4MB <= 51.2MB
  int2* bkt1 = (int2*)r2;                          // 64*sub1 entries
  int2* bkt2 = bkt1 + (size_t)64 * sub1;           // 64*sub2 entries

  auto blocks = [](long long t, int bs) { return (int)((t + bs - 1) / bs); };
  const int NB = blocks(n, 512);     // 98
  const int PA1 = 1024, PA2 = 2048;  // bucketize blocks (mult of 8)
  const int SB = blocks(n, 4);       // spmm blocks per graph

  // embed (independent of CSR build)
  embed_gemm_relu<<<blocks(n / 4, 4), 256, 0, stream>>>(x, w_embed, r0, r0h,
                                                        n / 4);

  // CSR build: bucketize -> LDS count -> shard-merge scan -> LDS scatter
  hipMemsetAsync(scur, 0, 128 * CPAD * sizeof(int), stream);
  bucketize2<<<PA1 + PA2, 256, 0, stream>>>(
      a1_idx, a1_val, E1, scur, bkt1, sub1, a2_idx, a2_val, E2,
      scur + 64 * CPAD, bkt2, sub2, PA1, PA1 + PA2, chunk);
  count_stripes<<<128, 256, 0, stream>>>(scur, bkt1, sub1, cnt81,
                                         scur + 64 * CPAD, bkt2, sub2, cnt82,
                                         n, chunk);
  scan_blocks2<<<2 * NB, 512, 0, stream>>>(cnt81, rs1, aux1, so1, cnt82, rs2,
                                           aux2, so2, n, NB);
  scan_aux2<<<2, 512, 0, stream>>>(aux1, aux2, NB);
  add_offsets2<<<2 * NB, 512, 0, stream>>>(rs1, aux1, E1, rs2, aux2, E2, n, NB);
  scatter_stripes<<<128, 256, 0, stream>>>(
      scur, bkt1, sub1, rs1, so1, ep1, scur + 64 * CPAD, bkt2, sub2, rs2, so2,
      ep2, n, chunk);

  // hop 1: r0h -> r1 [n,128] f32 + r1h f16  (ReLU fused)
  spmm_h1<<<2 * SB, 256, 0, stream>>>(rs1, ep1, rs2, ep2, r0h, r1, r1h, n, SB);
  // hop 2: r1h -> r2 [n,256] f32  (ReLU fused)
  spmm_h2<<<2 * SB, 256, 0, stream>>>(rs1, ep1, rs2, ep2, r1h, r2, n, SB);

  classify_softmax<<<blocks(n, 4), 256, 0, stream>>>(r0, r1, r2, w_classify,
                                                     out, n);
}